// Round 2
// baseline (715.176 us; speedup 1.0000x reference)
//
#include <hip/hip_runtime.h>

// BackprojectDepth — R6 DIAGNOSTIC (delay probe).
//
// R5 (nt -> cached stores) was exactly neutral (311.9 -> 314.3 us), killing
// the store-path theory. The kernel has never appeared in the rocprof top-5
// (all slots taken by the harness's 1 GiB poison fill @ ~167 us), so we
// cannot see its true duration or its FETCH/WRITE sizes. Two stories fit:
//   A) kernel ~50 us (write roofline), timed region dominated by harness
//      reset (~265 us fixed) -> all kernel edits are irrelevant.
//   B) kernel ~147 us (2.2 TB/s) via a mechanism common to nt+cached paths.
//
// This round adds a ~250 us dependent-FMA chain (output-invariant, kept
// alive with asm volatile) to push the kernel into the top-5 table. From
// the table we read its true dur D and its own FETCH/WRITE counters.
//   F = dur_us_total - D  (fixed harness overhead)
//   baseline kernel time = 314 - F.
// Pre-committed: F ~250-270 -> kernel was at roofline, declare ROOFLINE.
//                F ~165-185 -> kernel is ~145 us, hunt with real counters.
// Memory behavior is IDENTICAL to R5 (same grid, loads, stores).

#define BB 32
#define HH 512
#define WW 1024
#define HWN (HH * WW)   // 524288

// ~8192 dependent FMAs per wave. Issue-bound estimate: 128 waves/CU x
// ~9k VALU instr x 2 cyc / 4 SIMDs ~= 590k cycles ~= 245 us added.
#define DELAY_ITER 1024

typedef float vf4 __attribute__((ext_vector_type(4)));

__global__ __launch_bounds__(256) void backproject_kernel(
    const float* __restrict__ depth,   // [B, 1, H, W]
    const float* __restrict__ invK,    // [B, 4, 4]
    const int*   __restrict__ dxy,     // [B, 2]
    float*       __restrict__ out)     // [B, 4, H*W]
{
    const int tid  = threadIdx.x;
    const int b    = blockIdx.y;                 // wave-uniform
    const int row0 = blockIdx.x * 2;             // block covers rows row0, row0+1
    const int xpix = tid * 4;                    // x pixel of this thread's quad
    const int n0   = row0 * WW + xpix;           // pixel index, row 0 of pair

    // Uniform (scalar) loads
    const float k00 = invK[b * 16 + 0];
    const float k01 = invK[b * 16 + 1];
    const float k02 = invK[b * 16 + 2];
    const float k10 = invK[b * 16 + 4];
    const float k11 = invK[b * 16 + 5];
    const float k12 = invK[b * 16 + 6];
    const float k20 = invK[b * 16 + 8];
    const float k21 = invK[b * 16 + 9];
    const float k22 = invK[b * 16 + 10];
    const float dx  = (float)dxy[b * 2 + 0];
    const float dy  = (float)dxy[b * 2 + 1];

    const float x0 = (float)xpix + dx;           // same x for both rows

    // Cached (L3-served) depth loads, one per row — each contiguous per wave
    const float* dbase = depth + (size_t)b * HWN + n0;
    const vf4 da = *(const vf4*)(dbase);
    const vf4 db = *(const vf4*)(dbase + WW);

    // ---- DELAY PROBE: ~8k dependent FMAs, output-invariant, not DCE-able ----
    {
        float z = da.x * 1.0000001f + 0.0000001f;
        #pragma unroll 1
        for (int i = 0; i < DELAY_ITER; ++i) {
            // 8 dependent FMAs per iteration
            z = __builtin_fmaf(z, 1.0000001f, 1.0e-9f);
            z = __builtin_fmaf(z, 1.0000001f, 1.0e-9f);
            z = __builtin_fmaf(z, 1.0000001f, 1.0e-9f);
            z = __builtin_fmaf(z, 1.0000001f, 1.0e-9f);
            z = __builtin_fmaf(z, 1.0000001f, 1.0e-9f);
            z = __builtin_fmaf(z, 1.0000001f, 1.0e-9f);
            z = __builtin_fmaf(z, 1.0000001f, 1.0e-9f);
            z = __builtin_fmaf(z, 1.0000001f, 1.0e-9f);
        }
        asm volatile("" :: "v"(z));  // keep chain live; never stored
    }
    // -------------------------------------------------------------------------

    float* outb = out + (size_t)b * 4 * HWN;
    const vf4 ones = {1.f, 1.f, 1.f, 1.f};

    #pragma unroll
    for (int h = 0; h < 2; ++h) {                // two rows
        const vf4   d = h ? db : da;
        const float y = (float)(row0 + h) + dy;
        const float c0 = k01 * y + k02;
        const float c1 = k11 * y + k12;
        const float c2 = k21 * y + k22;

        vf4 r0, r1, r2;
        r0.x = d.x * (k00 * (x0 + 0.f) + c0);
        r0.y = d.y * (k00 * (x0 + 1.f) + c0);
        r0.z = d.z * (k00 * (x0 + 2.f) + c0);
        r0.w = d.w * (k00 * (x0 + 3.f) + c0);

        r1.x = d.x * (k10 * (x0 + 0.f) + c1);
        r1.y = d.y * (k10 * (x0 + 1.f) + c1);
        r1.z = d.z * (k10 * (x0 + 2.f) + c1);
        r1.w = d.w * (k10 * (x0 + 3.f) + c1);

        r2.x = d.x * (k20 * (x0 + 0.f) + c2);
        r2.y = d.y * (k20 * (x0 + 1.f) + c2);
        r2.z = d.z * (k20 * (x0 + 2.f) + c2);
        r2.w = d.w * (k20 * (x0 + 3.f) + c2);

        const int n = n0 + h * WW;
        *(vf4*)(outb + 0 * HWN + n) = r0;
        *(vf4*)(outb + 1 * HWN + n) = r1;
        *(vf4*)(outb + 2 * HWN + n) = r2;
        *(vf4*)(outb + 3 * HWN + n) = ones;
    }
}

extern "C" void kernel_launch(void* const* d_in, const int* in_sizes, int n_in,
                              void* d_out, int out_size, void* d_ws, size_t ws_size,
                              hipStream_t stream) {
    const float* depth = (const float*)d_in[0];
    const float* invK  = (const float*)d_in[1];
    const int*   dxy   = (const int*)d_in[2];
    float*       out   = (float*)d_out;

    dim3 grid(HH / 2, BB);   // 256 x 32 blocks, each does 2 rows of one batch
    backproject_kernel<<<grid, 256, 0, stream>>>(depth, invK, dxy, out);
}

// Round 3
// 317.522 us; speedup vs baseline: 2.2524x; 2.2524x over previous
//
#include <hip/hip_runtime.h>

// BackprojectDepth — R7: persistent-ish blocks + front-loaded depth reads.
//
// R6 delay-probe findings: kernel's true counters are clean (WRITE = 268 MB
// exact, FETCH = 33 MB, no amplification); fixed harness overhead F ~190 us;
// baseline kernel ~124 us = 2.4 TB/s, 2.6x off the 6.4 TB/s the poison fill
// sustains on the SAME buffer. Probe occupancy was 58% with 20 VGPR / 0 LDS:
// nothing architectural caps it — the 8192 tiny blocks (~1 us lifetime,
// 2 loads -> ~900cy HBM stall -> 8 stores -> die) starve the CUs on block
// refill and cap memory-level parallelism.
//
// R7 (Guideline 11): grid 8192 -> 2048 blocks (8/CU), each block owns 8 full
// rows (128 KB written). Each thread issues ALL 8 depth loads up front
// (8 outstanding VMEM loads), then computes/stores row by row — rows 1..7's
// load latency hides under row 0's stores. Same traffic, same per-instruction
// store pattern (contiguous aligned 1 KB wave segments), 4x block lifetime.

#define BB 32
#define HH 512
#define WW 1024
#define HWN (HH * WW)        // 524288
#define RPB 8                // rows per block

typedef float vf4 __attribute__((ext_vector_type(4)));

__global__ __launch_bounds__(256) void backproject_kernel(
    const float* __restrict__ depth,   // [B, 1, H, W]
    const float* __restrict__ invK,    // [B, 4, 4]
    const int*   __restrict__ dxy,     // [B, 2]
    float*       __restrict__ out)     // [B, 4, H*W]
{
    const int tid  = threadIdx.x;
    const int b    = blockIdx.y;                 // wave-uniform
    const int row0 = blockIdx.x * RPB;           // block covers rows row0..row0+7
    const int xpix = tid * 4;                    // x pixel of this thread's quad

    // Uniform (scalar) loads
    const float k00 = invK[b * 16 + 0];
    const float k01 = invK[b * 16 + 1];
    const float k02 = invK[b * 16 + 2];
    const float k10 = invK[b * 16 + 4];
    const float k11 = invK[b * 16 + 5];
    const float k12 = invK[b * 16 + 6];
    const float k20 = invK[b * 16 + 8];
    const float k21 = invK[b * 16 + 9];
    const float k22 = invK[b * 16 + 10];
    const float dx  = (float)dxy[b * 2 + 0];
    const float dy  = (float)dxy[b * 2 + 1];

    const float x0 = (float)xpix + dx;           // same x for all rows

    // Front-load ALL depth reads: 8 outstanding VMEM loads before any store.
    const float* dbase = depth + (size_t)b * HWN + row0 * WW + xpix;
    vf4 d[RPB];
    #pragma unroll
    for (int h = 0; h < RPB; ++h)
        d[h] = *(const vf4*)(dbase + h * WW);

    float* outb = out + (size_t)b * 4 * HWN;
    const vf4 ones = {1.f, 1.f, 1.f, 1.f};

    #pragma unroll
    for (int h = 0; h < RPB; ++h) {
        const float y  = (float)(row0 + h) + dy;
        const float c0 = k01 * y + k02;
        const float c1 = k11 * y + k12;
        const float c2 = k21 * y + k22;
        const vf4   dd = d[h];

        vf4 r0, r1, r2;
        r0.x = dd.x * (k00 * (x0 + 0.f) + c0);
        r0.y = dd.y * (k00 * (x0 + 1.f) + c0);
        r0.z = dd.z * (k00 * (x0 + 2.f) + c0);
        r0.w = dd.w * (k00 * (x0 + 3.f) + c0);

        r1.x = dd.x * (k10 * (x0 + 0.f) + c1);
        r1.y = dd.y * (k10 * (x0 + 1.f) + c1);
        r1.z = dd.z * (k10 * (x0 + 2.f) + c1);
        r1.w = dd.w * (k10 * (x0 + 3.f) + c1);

        r2.x = dd.x * (k20 * (x0 + 0.f) + c2);
        r2.y = dd.y * (k20 * (x0 + 1.f) + c2);
        r2.z = dd.z * (k20 * (x0 + 2.f) + c2);
        r2.w = dd.w * (k20 * (x0 + 3.f) + c2);

        const int n = (row0 + h) * WW + xpix;
        *(vf4*)(outb + 0 * HWN + n) = r0;
        *(vf4*)(outb + 1 * HWN + n) = r1;
        *(vf4*)(outb + 2 * HWN + n) = r2;
        *(vf4*)(outb + 3 * HWN + n) = ones;
    }
}

extern "C" void kernel_launch(void* const* d_in, const int* in_sizes, int n_in,
                              void* d_out, int out_size, void* d_ws, size_t ws_size,
                              hipStream_t stream) {
    const float* depth = (const float*)d_in[0];
    const float* invK  = (const float*)d_in[1];
    const int*   dxy   = (const int*)d_in[2];
    float*       out   = (float*)d_out;

    dim3 grid(HH / RPB, BB);   // 64 x 32 = 2048 blocks (8/CU), 8 rows each
    backproject_kernel<<<grid, 256, 0, stream>>>(depth, invK, dxy, out);
}